// Round 15
// baseline (178.961 us; speedup 1.0000x reference)
//
#include <hip/hip_runtime.h>
#include <hip/hip_bf16.h>
#include <stdint.h>

#define B_   4
#define C_   128
#define H_   128
#define W_   128
#define O_   128
#define HW_  16384
#define KK   9
#define KD   1152          // C_*KK
#define TM   32            // pixels per block
#define CLD  136           // 128 + 8 pad elems per pixel-row per chunk

typedef float f32x4 __attribute__((ext_vector_type(4)));
typedef short s16x8 __attribute__((ext_vector_type(8)));
typedef uint32_t u32x4 __attribute__((ext_vector_type(4)));

__device__ __forceinline__ uint32_t f2bf(float f) {
  uint32_t u = __builtin_bit_cast(uint32_t, f);
  u += 0x7FFFu + ((u >> 16) & 1u);   // RNE
  return u >> 16;
}
__device__ __forceinline__ float bflo(uint32_t v) { return __builtin_bit_cast(float, v << 16); }
__device__ __forceinline__ float bfhi(uint32_t v) { return __builtin_bit_cast(float, v & 0xFFFF0000u); }
__device__ __forceinline__ uint32_t pk2bf(float lo, float hi) {
  return f2bf(lo) | (f2bf(hi) << 16);
}

// ---------------- x: (B,C,H,W) f32 -> (B,HW,C) bf16 (vectorized) ----------------
__global__ __launch_bounds__(256) void k_transpose(const float* __restrict__ x,
                                                   uint16_t* __restrict__ xt) {
  __shared__ uint32_t upk[64][33];
  int tid = threadIdx.x;
  int bid = blockIdx.x;
  int b   = bid >> 9;
  int r   = bid & 511;
  int c0  = (r >> 8) << 6;
  int hw0 = (r & 255) << 6;

#pragma unroll
  for (int p = 0; p < 2; ++p) {
    int cp = p * 16 + (tid >> 4);
    int c  = c0 + (cp << 1);
    int hw = (tid & 15) << 2;
    const float* s0 = x + ((size_t)(b * C_ + c) * HW_) + hw0 + hw;
    f32x4 v0 = *reinterpret_cast<const f32x4*>(s0);
    f32x4 v1 = *reinterpret_cast<const f32x4*>(s0 + HW_);
#pragma unroll
    for (int qq = 0; qq < 4; ++qq)
      upk[hw + qq][cp] = pk2bf(v0[qq], v1[qq]);
  }
  __syncthreads();
#pragma unroll
  for (int p = 0; p < 2; ++p) {
    int hwl = p * 32 + (tid >> 3);
    int jj  = tid & 7;
    u32x4 o;
#pragma unroll
    for (int i = 0; i < 4; ++i) o[i] = upk[hwl][jj * 4 + i];
    *reinterpret_cast<u32x4*>(xt + ((size_t)(b * HW_ + hw0 + hwl) * C_) + c0 + jj * 8) = o;
  }
}

// ---------------- weight: (O,C,3,3) f32 -> wT[o][kpos*128+c] bf16 ----------------
__global__ __launch_bounds__(256) void k_weight(const float* __restrict__ w,
                                                uint16_t* __restrict__ wt) {
  int gg = blockIdx.x * 256 + threadIdx.x;
  int o   = gg / KD;
  int rem = gg - o * KD;
  int kp  = rem >> 7;
  int c   = rem & 127;
  wt[gg] = (uint16_t)f2bf(w[(o * C_ + c) * KK + kp]);
}

// ---------------- main: 9-chunk pipeline, gather+weight register prefetch ----------------
__global__ __launch_bounds__(512, 4) void k_main(const float* __restrict__ off,
                                                 const uint16_t* __restrict__ xt,
                                                 const uint16_t* __restrict__ wt,
                                                 float* __restrict__ out) {
  __shared__ __align__(16) uint16_t ps2[2][TM][CLD];   // 17,408 B
  int tid  = threadIdx.x;
  int lane = tid & 63, wv = tid >> 6;

  int sbid = ((blockIdx.x & 7) << 8) | (blockIdx.x >> 3);   // XCD swizzle, bijective
  int p0   = sbid * TM;
  int b    = p0 >> 14;
  int hw0  = p0 & (HW_ - 1);

  // Phase-A roles
  int q   = lane >> 4;
  int j   = lane & 15;
  int pix = (wv << 2) + q;
  int hw  = hw0 + pix;
  int h = hw >> 7, w = hw & 127;
  uint32_t cb = (uint32_t)(j << 4);
  const char*  xtb  = (const char*)(xt + (size_t)b * HW_ * C_);
  const float* offb = off + (size_t)b * 18 * HW_ + hw;

  // Phase-B roles
  int r = lane & 15, g = lane >> 4;
  const uint16_t* wrow = wt + (wv * 16 + r) * KD + g * 8;

  f32x4 acc0 = {0.f,0.f,0.f,0.f}, acc1 = {0.f,0.f,0.f,0.f};

  float oyv[9], oxv[9];
  u32x4 g0, g1, g2, g3;
  float w00, w01, w10, w11;
  s16x8 wbuf[2][4];                     // weight fragments, double-buffered in regs

#define GATHER_TAP(K)                                                          \
  {                                                                            \
    const int kdy = (K)/3 - 1, kdx = (K)%3 - 1;                                \
    float py = (float)(h + kdy) + oyv[K];                                      \
    float px = (float)(w + kdx) + oxv[K];                                      \
    float yf = floorf(py), xf = floorf(px);                                    \
    float wy = py - yf, wx = px - xf;                                          \
    int y0 = (int)yf, x0 = (int)xf;                                            \
    int y1 = y0 + 1, x1 = x0 + 1;                                              \
    int y0c = min(max(y0,0),H_-1), y1c = min(max(y1,0),H_-1);                  \
    int x0c = min(max(x0,0),W_-1), x1c = min(max(x1,0),W_-1);                  \
    bool vy0 = (unsigned)y0 < (unsigned)H_, vy1 = (unsigned)y1 < (unsigned)H_; \
    bool vx0 = (unsigned)x0 < (unsigned)W_, vx1 = (unsigned)x1 < (unsigned)W_; \
    float ay = 1.f - wy, ax = 1.f - wx;                                        \
    w00 = (vy0 && vx0) ? ay*ax : 0.f;                                          \
    w01 = (vy0 && vx1) ? ay*wx : 0.f;                                          \
    w10 = (vy1 && vx0) ? wy*ax : 0.f;                                          \
    w11 = (vy1 && vx1) ? wy*wx : 0.f;                                          \
    uint32_t o00 = ((uint32_t)((y0c<<7)+x0c)<<8) + cb;                         \
    uint32_t o01 = ((uint32_t)((y0c<<7)+x1c)<<8) + cb;                         \
    uint32_t o10 = ((uint32_t)((y1c<<7)+x0c)<<8) + cb;                         \
    uint32_t o11 = ((uint32_t)((y1c<<7)+x1c)<<8) + cb;                         \
    g0 = *reinterpret_cast<const u32x4*>(xtb + o00);                           \
    g1 = *reinterpret_cast<const u32x4*>(xtb + o01);                           \
    g2 = *reinterpret_cast<const u32x4*>(xtb + o10);                           \
    g3 = *reinterpret_cast<const u32x4*>(xtb + o11);                           \
  }

#define INTERP_TAP(BUF)                                                        \
  {                                                                            \
    u32x4 ov;                                                                  \
    _Pragma("unroll")                                                          \
    for (int i = 0; i < 4; ++i) {                                              \
      float lo = w00*bflo(g0[i]) + w01*bflo(g1[i]) + w10*bflo(g2[i]) + w11*bflo(g3[i]); \
      float hi = w00*bfhi(g0[i]) + w01*bfhi(g1[i]) + w10*bfhi(g2[i]) + w11*bfhi(g3[i]); \
      ov[i] = pk2bf(lo, hi);                                                   \
    }                                                                          \
    *reinterpret_cast<u32x4*>(&ps2[BUF][pix][j*8]) = ov;                       \
  }

  // prologue: offsets 0..2, weights for tap 0, tap 0 staged into buf 0
  oyv[0] = offb[0];        oxv[0] = offb[HW_];
  oyv[1] = offb[2*HW_];    oxv[1] = offb[3*HW_];
  oyv[2] = offb[4*HW_];    oxv[2] = offb[5*HW_];
#pragma unroll
  for (int s = 0; s < 4; ++s)
    wbuf[0][s] = *reinterpret_cast<const s16x8*>(wrow + s * 32);
  GATHER_TAP(0);
  INTERP_TAP(0);
  __syncthreads();

#pragma unroll
  for (int k = 0; k < 9; ++k) {
    if (k < 8) {
      // issue next tap's weight fragments FIRST (static addresses, no deps)
#pragma unroll
      for (int s = 0; s < 4; ++s)
        wbuf[(k+1)&1][s] = *reinterpret_cast<const s16x8*>(wrow + ((k+1)*4 + s) * 32);
      GATHER_TAP(k+1);                  // then next tap's 4 gathers
    }
    if (k < 6) {                        // offsets 3 taps ahead
      oyv[k+3] = offb[(2*(k+3))*HW_];
      oxv[k+3] = offb[(2*(k+3)+1)*HW_];
    }
    {                                   // MFMA on chunk k (buf k&1), weights from regs
      const uint16_t* b0 = &ps2[k&1][r][g*8];
      const uint16_t* b1 = &ps2[k&1][16+r][g*8];
#pragma unroll
      for (int s = 0; s < 4; ++s) {
        s16x8 a0 = *reinterpret_cast<const s16x8*>(b0 + s*32);
        s16x8 a1 = *reinterpret_cast<const s16x8*>(b1 + s*32);
        acc0 = __builtin_amdgcn_mfma_f32_16x16x32_bf16(a0, wbuf[k&1][s], acc0, 0,0,0);
        acc1 = __builtin_amdgcn_mfma_f32_16x16x32_bf16(a1, wbuf[k&1][s], acc1, 0,0,0);
      }
    }
    if (k < 8) INTERP_TAP((k+1)&1);     // finish next tap into other buf
    __syncthreads();
  }

  // ---- Phase C: accumulators -> LDS (reuse ps2) -> coalesced store ----
  float* lout = reinterpret_cast<float*>(&ps2[0][0][0]);  // 16,896 B <= 17,408
  {
    int o = wv * 16 + r;
#pragma unroll
    for (int i = 0; i < 4; ++i) lout[o * 33 + (g << 2) + i] = acc0[i];
#pragma unroll
    for (int i = 0; i < 4; ++i) lout[o * 33 + 16 + (g << 2) + i] = acc1[i];
  }
  __syncthreads();
  {
    int pl = tid & 31, og = tid >> 5;
    float* obase = out + (size_t)(b * O_) * HW_ + hw0 + pl;
#pragma unroll
    for (int i = 0; i < 8; ++i) {
      int o = og * 8 + i;
      obase[(size_t)o * HW_] = lout[o * 33 + pl];
    }
  }
#undef GATHER_TAP
#undef INTERP_TAP
}

extern "C" void kernel_launch(void* const* d_in, const int* in_sizes, int n_in,
                              void* d_out, int out_size, void* d_ws, size_t ws_size,
                              hipStream_t stream) {
  const float* x   = (const float*)d_in[0];
  const float* off = (const float*)d_in[1];
  const float* wgt = (const float*)d_in[2];
  float* out = (float*)d_out;

  uint16_t* xt = (uint16_t*)d_ws;                      // 16 MB
  uint16_t* wt = xt + (size_t)B_ * HW_ * C_;           // 288 KB

  k_transpose<<<2048, 256, 0, stream>>>(x, xt);
  k_weight<<<576, 256, 0, stream>>>(wgt, wt);
  k_main<<<2048, 512, 0, stream>>>(off, xt, wt, out);
}